// Round 15
// baseline (26.944 us; speedup 1.0000x reference)
//
#include <hip/hip_runtime.h>
#include <hip/hip_bf16.h>

// HalfKP input layer, fully-fused king-grouped MFMA (2 dispatches):
//   per king k: D = A_k (nc x 672 bf16 0/1) x W_k (672x256 -> bf16)
//   out[b,c] = bias[c] + D[entry(b,0)] + D[entry(b,1)]
// B=1024, K=64, F=640(+row 640), C=256. W is (64,641,256) fp32 = 42 MB.
//
// R15 vs R14: plateau 27-29us across 4 different mfma structures => fixed
// costs dominate (3 dispatch gaps + serial phases). (a) pack_masks fused in:
// per chunk each wave batch-loads 40 piece words (all in flight, unlike R13's
// 2-deep ballot chain), then 40 register ballots. (b) T14 async-stage: issue
// all 12 staging float4 loads FIRST, run list build while in flight, then
// pack+ds_write_b128. (c) 2 dispatches total. MFMA/reduce/D-write verbatim
// R14 (HW-verified absmax 0.5).

#define F_DIM 640
#define C_DIM 256
#define SLAB_STRIDE (641 * 256)   // floats per king slab
#define NKING 64
#define LCAP 256                  // list capacity per king
#define NC_MAX 64                 // max 64-entry chunks (nent <= 4096)
#define WPAD 36                   // LDS row stride in u32 (144B, 16B-aligned)

// ws layout (bytes)
#define WS_PART_OFF 0                        // 2*1024*256*4 = 2 MB
#define WS_NEED (2 * 1024 * 256 * 4)

typedef float  f32x4  __attribute__((ext_vector_type(4)));
typedef short  bf16x8 __attribute__((ext_vector_type(8)));

__device__ __forceinline__ unsigned f2bf_pk(float a, float b) {
    // two RNE fp32->bf16, packed lo|hi (bit-exact, HW-verified R8-R14)
    union { float f; unsigned u; } x, y;
    x.f = a; y.f = b;
    const unsigned ra = (x.u + 0x7FFFu + ((x.u >> 16) & 1u)) >> 16;
    const unsigned rb = (y.u + 0x7FFFu + ((y.u >> 16) & 1u)) >> 16;
    return (ra & 0xFFFFu) | (rb << 16);
}

__device__ __forceinline__ bf16x8 mk_a8(unsigned m32, int g) {
    // A-frag: 8 bf16 0/1 from byte g of a 32-bit window mask (k = g*8 + j)
    const unsigned by = (m32 >> (g * 8)) & 0xFFu;
    union { unsigned u[4]; bf16x8 v; } r;
    #pragma unroll
    for (int i = 0; i < 4; ++i)
        r.u[i] = (((by >> (2 * i)) & 1u) ? 0x3F80u : 0u) |
                 (((by >> (2 * i + 1)) & 1u) ? 0x3F800000u : 0u);
    return r.v;
}

__global__ __launch_bounds__(512, 4)
void halfkp_fused(const float* __restrict__ W,        // (64,641,256)
                  const int* __restrict__ pieces,     // (B,640) int32 0/1
                  const int* __restrict__ kings,      // flat (B*2)
                  float* __restrict__ partial,        // (2,B,256)
                  int nent)
{
    const int k  = blockIdx.x;
    const int cq = blockIdx.y;               // 0..7, 32 cols each
    const int t  = threadIdx.x;
    const int wv = t >> 6, lane = t & 63;
    const int mt  = wv & 1;                  // M-tile 0..1
    const int ntc = (wv >> 1) & 1;           // N-half 0..1
    const int kh  = wv >> 2;                 // K-half 0..1
    const int li = lane & 15, g = lane >> 4;
    const int colL = ntc * 16 + li;
    const int colG = cq * 32 + colL;

    __shared__ unsigned s_W[336 * WPAD];     // 48.4 KB bf16-pair x 32 cols
    __shared__ int s_ent[LCAP];
    __shared__ int s_cb[NC_MAX + 1];
    __shared__ unsigned s_m32[32][21];       // per-row window masks
    __shared__ f32x4 s_red[4][64];           // pairwise K-reduce
    __shared__ int s_nk;

    // ---- A: issue W staging loads (12 float4 in flight per thread) ----
    const float* __restrict__ Wq = W + (size_t)k * SLAB_STRIDE + cq * 32;
    float4 ve[6], vo[6];
    #pragma unroll
    for (int it = 0; it < 6; ++it) {
        const int task = t + (it << 9);
        if (task < 336 * 8) {
            const int fp = task >> 3, c4 = task & 7;
            const int fe = min(2 * fp, F_DIM);
            const int fo = min(2 * fp + 1, F_DIM);
            ve[it] = *(const float4*)&Wq[(size_t)fe * C_DIM + c4 * 4];
            vo[it] = *(const float4*)&Wq[(size_t)fo * C_DIM + c4 * 4];
        }
    }

    // ---- B: in-block list build (R10-verified), overlaps staging latency ----
    {
        const int NC = nent >> 6;            // 64-entry chunks
        const int nit = NC >> 3;             // chunks per wave (8 waves)
        unsigned long long mm[8];
        #pragma unroll
        for (int it = 0; it < 8; ++it) {
            if (it < nit) {
                const int c = wv + (it << 3);
                const int kk = kings[(c << 6) + lane];
                mm[it] = __ballot(kk == k);
                if (lane == 0) s_cb[c] = (int)__popcll(mm[it]);
            }
        }
        __syncthreads();
        if (t == 0) {
            int s = 0;
            for (int c = 0; c < NC; ++c) { const int v = s_cb[c]; s_cb[c] = s; s += v; }
            s_nk = min(s, LCAP);
        }
        __syncthreads();
        const unsigned long long lt = (1ull << lane) - 1ull;
        #pragma unroll
        for (int it = 0; it < 8; ++it) {
            if (it < nit) {
                const int c = wv + (it << 3);
                if ((mm[it] >> lane) & 1ull) {
                    const int pos = s_cb[c] + (int)__popcll(mm[it] & lt);
                    if (pos < LCAP) s_ent[pos] = (c << 6) + lane;
                }
            }
        }
    }

    // ---- C: pack staged W and write to LDS (ds_write_b128) ----
    #pragma unroll
    for (int it = 0; it < 6; ++it) {
        const int task = t + (it << 9);
        if (task < 336 * 8) {
            const int fp = task >> 3, c4 = task & 7;
            union { unsigned u[4]; f32x4 v; } pk;
            pk.u[0] = f2bf_pk(ve[it].x, vo[it].x);
            pk.u[1] = f2bf_pk(ve[it].y, vo[it].y);
            pk.u[2] = f2bf_pk(ve[it].z, vo[it].z);
            pk.u[3] = f2bf_pk(ve[it].w, vo[it].w);
            *(f32x4*)&s_W[fp * WPAD + c4 * 4] = pk.v;
        }
    }
    __syncthreads();                          // covers list scatter + s_W
    const int n_k = s_nk;

    for (int mb = 0; mb < n_k; mb += 32) {
        const int nc = min(n_k - mb, 32);

        // ---- fused mask build: batch-load 40 words, then 40 ballots ----
        int pv[4][10];
        #pragma unroll
        for (int j = 0; j < 4; ++j) {
            const int r = (wv << 2) + j;      // wave-uniform row
            const int id = (r < nc) ? s_ent[mb + r] : -1;
            if (id >= 0) {
                const int* __restrict__ pb = pieces + (size_t)(id >> 1) * F_DIM;
                #pragma unroll
                for (int w2 = 0; w2 < 10; ++w2) pv[j][w2] = pb[w2 * 64 + lane];
            } else {
                #pragma unroll
                for (int w2 = 0; w2 < 10; ++w2) pv[j][w2] = 0;
            }
        }
        #pragma unroll
        for (int j = 0; j < 4; ++j) {
            const int r = (wv << 2) + j;
            const int id = (r < nc) ? s_ent[mb + r] : -1;
            #pragma unroll
            for (int w2 = 0; w2 < 10; ++w2) {
                const unsigned long long m64 = __ballot(pv[j][w2] != 0);
                if (lane == 0) {
                    s_m32[r][2 * w2]     = (unsigned)m64;
                    s_m32[r][2 * w2 + 1] = (unsigned)(m64 >> 32);
                }
            }
            if (lane == 0) s_m32[r][20] = (id >= 0) ? 1u : 0u;  // row 640
        }
        __syncthreads();

        // ---- MFMA over this wave's K-half; B-frags from LDS (R14 verbatim) ----
        const unsigned* mrow = s_m32[mt * 16 + li];
        f32x4 acc = {0.f, 0.f, 0.f, 0.f};
        {
            const int ks_beg = kh ? 10 : 0;
            const int ks_end = kh ? 21 : 10;
            #pragma unroll 2
            for (int ks = ks_beg; ks < ks_end; ++ks) {
                const unsigned* bp = &s_W[(ks * 16 + g * 4) * WPAD + colL];
                union { unsigned u[4]; bf16x8 v; } bb;
                #pragma unroll
                for (int jj = 0; jj < 4; ++jj)
                    bb.u[jj] = bp[jj * WPAD];
                const bf16x8 af = mk_a8(mrow[ks], g);
                acc = __builtin_amdgcn_mfma_f32_16x16x32_bf16(af, bb.v, acc, 0, 0, 0);
            }
        }
        if (kh == 1) s_red[wv & 3][lane] = acc;      // publish K-half 1
        __syncthreads();
        if (kh == 0) {
            acc += s_red[wv & 3][lane];              // partner (mt,ntc) wave
            // D: reg i -> row = mt*16 + 4*g + i, col = colG (m89-verified)
            #pragma unroll
            for (int i = 0; i < 4; ++i) {
                const int row = mt * 16 + 4 * g + i;
                if (row < nc) {
                    const int id = s_ent[mb + row];
                    partial[(((size_t)(id & 1)) * 1024 + (id >> 1)) * C_DIM + colG] = acc[i];
                }
            }
        }
        __syncthreads();   // protect s_m32/s_red before next chunk
    }
}

__global__ __launch_bounds__(256)
void finalize(const float* __restrict__ partial,
              const float* __restrict__ bias,
              float* __restrict__ out)
{
    const int i = blockIdx.x * 256 + threadIdx.x;    // float4 index, B*64 total
    const float4 b4 = ((const float4*)bias)[i & 63];
    const float4 p0 = ((const float4*)partial)[i];
    const float4 p1 = ((const float4*)partial)[1024 * 64 + i];
    float4 o;
    o.x = b4.x + p0.x + p1.x;
    o.y = b4.y + p0.y + p1.y;
    o.z = b4.z + p0.z + p1.z;
    o.w = b4.w + p0.w + p1.w;
    ((float4*)out)[i] = o;
}

// ---- fallback (R3 path) if ws is too small ----
__global__ __launch_bounds__(256)
void halfkp_fallback(const int* __restrict__ pieces, const int* __restrict__ kings,
                     const float* __restrict__ W, const float* __restrict__ bias,
                     float* __restrict__ out)
{
    const int b = blockIdx.x;
    const int c = threadIdx.x;
    const int lane = c & 63;
    const int k0 = kings[2 * b + 0];
    const int k1 = kings[2 * b + 1];
    const float* W0 = W + (size_t)k0 * SLAB_STRIDE + c;
    const float* W1 = W + (size_t)k1 * SLAB_STRIDE + c;
    float acc = bias[c] + W0[640 * 256] + W1[640 * 256];
    const int* pi = pieces + (size_t)b * F_DIM;
    #pragma unroll
    for (int ch = 0; ch < 10; ++ch) {
        int v = pi[ch * 64 + lane];
        unsigned long long m = __ballot(v != 0);
        const float* b0 = W0 + ch * 64 * 256;
        const float* b1 = W1 + ch * 64 * 256;
        while (m) {
            const int f = __builtin_ctzll(m);
            m &= m - 1;
            acc += b0[f * 256] + b1[f * 256];
        }
    }
    out[(size_t)b * C_DIM + c] = acc;
}

extern "C" void kernel_launch(void* const* d_in, const int* in_sizes, int n_in,
                              void* d_out, int out_size, void* d_ws, size_t ws_size,
                              hipStream_t stream) {
    const int* pieces = (const int*)d_in[0];   // (1024, 640) int32 bools
    const int* kings  = (const int*)d_in[1];   // (1024, 2) int32
    const float* W    = (const float*)d_in[2]; // (64, 641, 256) f32
    const float* bias = (const float*)d_in[3]; // (256,) f32
    float* out        = (float*)d_out;         // (1024, 256) f32

    const int B = in_sizes[1] / 2;             // 1024
    const int nent = 2 * B;

    if (ws_size < (size_t)WS_NEED) {
        halfkp_fallback<<<dim3(B), dim3(C_DIM), 0, stream>>>(pieces, kings, W, bias, out);
        return;
    }

    float* part = (float*)((char*)d_ws + WS_PART_OFF);

    halfkp_fused<<<dim3(NKING, 8), dim3(512), 0, stream>>>(W, pieces, kings, part, nent);
    finalize<<<dim3(B * 64 / 256), dim3(256), 0, stream>>>(part, bias, out);
}